// Round 22
// baseline (50.335 us; speedup 1.0000x reference)
//
#include <hip/hip_runtime.h>
#include <hip/hip_bf16.h>

using u64 = unsigned long long;

constexpr int Bb    = 4;
constexpr int Nn    = 2048;
constexpr int INDIM = 64;
constexpr int HID   = 128;      // HIDDEN == OUT_DIM == 128
constexpr int NW    = Nn / 64;  // mask words per row = 32
constexpr int NT    = 16;       // 128-wide tile count per dim
constexpr int NTRI  = NT * (NT + 1) / 2;   // 136 upper-triangle tiles

// ---------------- fused: [adj 128x128 upper-triangle tiles + transpose write]
//                      || [projhid]
// B-tile reads split into 2x float4 at tx*4 / 64+tx*4: 16-lane stride 16B ->
// 2-way bank aliasing (free) instead of 4-way conflict at stride 32B.
struct AdjS {
    float As[32][132];          // k-major A tile (128 i-rows)
    float Bs[32][132];          // k-major B tile (128 j-rows)
    float nA[128];              // rsqrt norms, i-rows
    float nB[128];              // rsqrt norms, j-rows
    unsigned char nib [128][32]; // direct nibbles:  nib[row][col/4]
    unsigned char nibT[128][32]; // transposed:      nibT[col][row/4]
};

__global__ __launch_bounds__(256) void k_adjproj(
        const float* __restrict__ emb, u64* __restrict__ maskw,
        const float* __restrict__ x,   const float* __restrict__ Wp,
        const float* __restrict__ bp,  const float* __restrict__ W1,
        const float* __restrict__ a1s, const float* __restrict__ a1d,
        float* __restrict__ hh1, float* __restrict__ s1s, float* __restrict__ s1d) {
    __shared__ __align__(16) unsigned char smem[sizeof(AdjS)];
    const int t = threadIdx.x;

    if (blockIdx.x < NTRI) {
        // -------- adj: upper-triangle 128x128 tile, 8x8 acc/thread, BK=32
        AdjS& S = *reinterpret_cast<AdjS*>(smem);
        int b = blockIdx.x, ti = 0, cum = 0;
        while (cum + (NT - ti) <= b) { cum += NT - ti; ++ti; }
        const int tj = ti + (b - cum);
        const bool diag = (ti == tj);
        const int i0 = ti * 128, j0 = tj * 128;

        const int tx = t & 15, ty = t >> 4;         // 16x16 thread grid
        const int sr = t >> 1, sh = (t & 1) * 16;   // staging: 2 threads/row, 16 floats

        float acc[8][8];
        #pragma unroll
        for (int a = 0; a < 8; ++a)
            #pragma unroll
            for (int c = 0; c < 8; ++c) acc[a][c] = 0.f;

        float sqa = 0.f, sqb = 0.f;

        for (int kc = 0; kc < HID; kc += 32) {
            const float* gA = emb + (size_t)(i0 + sr) * HID + kc + sh;
            const float* gB = emb + (size_t)(j0 + sr) * HID + kc + sh;
            #pragma unroll
            for (int e = 0; e < 16; e += 4) {
                const float4 va = *reinterpret_cast<const float4*>(gA + e);
                const float4 vb = *reinterpret_cast<const float4*>(gB + e);
                S.As[sh + e + 0][sr] = va.x; S.As[sh + e + 1][sr] = va.y;
                S.As[sh + e + 2][sr] = va.z; S.As[sh + e + 3][sr] = va.w;
                sqa += va.x * va.x + va.y * va.y + va.z * va.z + va.w * va.w;
                S.Bs[sh + e + 0][sr] = vb.x; S.Bs[sh + e + 1][sr] = vb.y;
                S.Bs[sh + e + 2][sr] = vb.z; S.Bs[sh + e + 3][sr] = vb.w;
                sqb += vb.x * vb.x + vb.y * vb.y + vb.z * vb.z + vb.w * vb.w;
            }
            __syncthreads();
            #pragma unroll 4
            for (int k = 0; k < 32; ++k) {
                float a[8], c[8];
                *reinterpret_cast<float4*>(&a[0]) = *reinterpret_cast<const float4*>(&S.As[k][ty * 8]);
                *reinterpret_cast<float4*>(&a[4]) = *reinterpret_cast<const float4*>(&S.As[k][ty * 8 + 4]);
                *reinterpret_cast<float4*>(&c[0]) = *reinterpret_cast<const float4*>(&S.Bs[k][tx * 4]);
                *reinterpret_cast<float4*>(&c[4]) = *reinterpret_cast<const float4*>(&S.Bs[k][64 + tx * 4]);
                #pragma unroll
                for (int ii = 0; ii < 8; ++ii)
                    #pragma unroll
                    for (int jj = 0; jj < 8; ++jj)
                        acc[ii][jj] += a[ii] * c[jj];
            }
            __syncthreads();
        }

        // staging partials -> per-row rsqrt norms (2 threads/row)
        {
            const float ta = sqa + __shfl_xor(sqa, 1, 64);
            if ((t & 1) == 0) S.nA[sr] = rsqrtf(ta + 1e-12f);
            const float tb = sqb + __shfl_xor(sqb, 1, 64);
            if ((t & 1) == 0) S.nB[sr] = rsqrtf(tb + 1e-12f);
        }
        __syncthreads();

        // cols owned: jj<4 -> tx*4+jj ; jj>=4 -> 64+tx*4+(jj-4). rows: ty*8+e.
        float rsi[8], rsj[8];
        #pragma unroll
        for (int e = 0; e < 8; ++e) rsi[e] = S.nA[ty * 8 + e];
        #pragma unroll
        for (int jj = 0; jj < 4; ++jj) {
            rsj[jj]     = S.nB[tx * 4 + jj];
            rsj[4 + jj] = S.nB[64 + tx * 4 + jj];
        }

        bool bit[8][8];
        #pragma unroll
        for (int e = 0; e < 8; ++e)
            #pragma unroll
            for (int jj = 0; jj < 8; ++jj)
                bit[e][jj] = (acc[e][jj] * rsi[e] * rsj[jj] > 0.5f);

        // direct nibbles: nib[row][n], n = col/4 (side0: n=tx, side1: n=16+tx)
        #pragma unroll
        for (int e = 0; e < 8; ++e) {
            unsigned n0 = 0, n1 = 0;
            #pragma unroll
            for (int jj = 0; jj < 4; ++jj) {
                if (bit[e][jj])     n0 |= (1u << jj);
                if (bit[e][4 + jj]) n1 |= (1u << jj);
            }
            S.nib[ty * 8 + e][tx]      = (unsigned char)n0;
            S.nib[ty * 8 + e][16 + tx] = (unsigned char)n1;
        }
        // transposed nibbles: nibT[col][n], n = row/4 (rows ty*8..+7 -> n = 2ty, 2ty+1)
        #pragma unroll
        for (int jj = 0; jj < 4; ++jj) {
            unsigned t00 = 0, t01 = 0, t10 = 0, t11 = 0;
            #pragma unroll
            for (int e = 0; e < 4; ++e) {
                if (bit[e][jj])         t00 |= (1u << e);
                if (bit[4 + e][jj])     t01 |= (1u << e);
                if (bit[e][4 + jj])     t10 |= (1u << e);
                if (bit[4 + e][4 + jj]) t11 |= (1u << e);
            }
            S.nibT[tx * 4 + jj][2 * ty]          = (unsigned char)t00;
            S.nibT[tx * 4 + jj][2 * ty + 1]      = (unsigned char)t01;
            S.nibT[64 + tx * 4 + jj][2 * ty]     = (unsigned char)t10;
            S.nibT[64 + tx * 4 + jj][2 * ty + 1] = (unsigned char)t11;
        }
        __syncthreads();

        if (t < 128) {                      // direct: row i0+t, words 2tj, 2tj+1
            u64 w0 = 0, w1 = 0;
            #pragma unroll
            for (int n = 0; n < 16; ++n) {
                w0 |= (u64)(S.nib[t][n] & 0xF)      << (4 * n);
                w1 |= (u64)(S.nib[t][16 + n] & 0xF) << (4 * n);
            }
            maskw[(size_t)(i0 + t) * NW + 2 * tj]     = w0;
            maskw[(size_t)(i0 + t) * NW + 2 * tj + 1] = w1;
        } else if (!diag) {                 // transpose: row j0+(t-128), words 2ti, 2ti+1
            const int c = t - 128;
            u64 w0 = 0, w1 = 0;
            #pragma unroll
            for (int n = 0; n < 16; ++n) {
                w0 |= (u64)(S.nibT[c][n] & 0xF)      << (4 * n);
                w1 |= (u64)(S.nibT[c][16 + n] & 0xF) << (4 * n);
            }
            maskw[(size_t)(j0 + c) * NW + 2 * ti]     = w0;
            maskw[(size_t)(j0 + c) * NW + 2 * ti + 1] = w1;
        }
    } else {
        // ---------------- projhid: 16 rows/block (two 128-thread halves x 8)
        float (*hl)[128] = reinterpret_cast<float(*)[128]>(smem);
        const int h  = t >> 7;          // half 0/1
        const int c  = t & 127;         // channel
        const int r0 = (blockIdx.x - NTRI) * 16 + h * 8;

        float acc[8];
        const float bias = bp[c];
        #pragma unroll
        for (int r = 0; r < 8; ++r) acc[r] = bias;
        #pragma unroll 4
        for (int k = 0; k < INDIM; ++k) {
            const float wp = Wp[k * HID + c];
            #pragma unroll
            for (int r = 0; r < 8; ++r)
                acc[r] += x[(size_t)(r0 + r) * INDIM + k] * wp;  // block-uniform -> s_load
        }
        #pragma unroll
        for (int r = 0; r < 8; ++r) hl[h * 8 + r][c] = acc[r];
        __syncthreads();

        float a2[8];
        #pragma unroll
        for (int r = 0; r < 8; ++r) a2[r] = 0.f;
        #pragma unroll 4
        for (int k = 0; k < HID; ++k) {
            const float w = W1[k * HID + c];
            #pragma unroll
            for (int r = 0; r < 8; ++r)
                a2[r] += hl[h * 8 + r][k] * w;                   // LDS broadcast
        }
        const float as = a1s[c], ad = a1d[c];
        #pragma unroll
        for (int r = 0; r < 8; ++r) {
            hh1[(size_t)(r0 + r) * HID + c] = a2[r];
            float vs = a2[r] * as;
            float vd = a2[r] * ad;
            #pragma unroll
            for (int m = 1; m < 32; m <<= 1) {
                vs += __shfl_xor(vs, m, 32);
                vd += __shfl_xor(vd, m, 32);
            }
            if ((c & 31) == 0) {
                s1s[(size_t)(r0 + r) * 4 + (c >> 5)] = vs;
                s1d[(size_t)(r0 + r) * 4 + (c >> 5)] = vd;
            }
        }
    }
}

// ------- fused: gat layer1 (+GELU) fast word-scan ; hh2 = g@W2 ; s2.
// 8 rows/block (1024 blocks), 128 threads (2 waves); wave scans 4 rows.
__global__ __launch_bounds__(128) void k_gathid2(
        const float* __restrict__ hh1,
        const float* __restrict__ s1s, const float* __restrict__ s1d,
        const u64* __restrict__ maskw, const float* __restrict__ b1v,
        const float* __restrict__ W2,
        const float* __restrict__ a2s, const float* __restrict__ a2d,
        float* __restrict__ hh2,
        float* __restrict__ s2s, float* __restrict__ s2d) {
    const int r0   = blockIdx.x * 8;
    const int bb   = r0 >> 11;          // batch index
    const int t    = threadIdx.x;
    const int wv   = t >> 6;            // wave 0/1
    const int lane = t & 63;
    const int h0   = lane >> 5, h1 = 2 + h0;
    __shared__ float gl[8][128];

    for (int rr = 0; rr < 4; ++rr) {
        const int r   = wv * 4 + rr;
        const int row = r0 + r, i = row & (Nn - 1);
        const u64* mrow = maskw + (size_t)i * NW;
        const u64 myw = (lane < NW) ? mrow[lane] : 0ULL;   // one coalesced round
        u64 nz = __ballot(myw != 0ULL);
        const float sd0 = s1d[(size_t)row * 4 + h0];
        const float sd1 = s1d[(size_t)row * 4 + h1];
        float m0 = -INFINITY, l0 = 0.f, a0 = 0.f;
        float m1 = -INFINITY, l1 = 0.f, a1 = 0.f;
        while (nz) {
            const int w = __builtin_ctzll(nz); nz &= nz - 1;
            u64 word = __shfl(myw, w, 64);
            while (word) {
                const int bit = __builtin_ctzll(word); word &= word - 1;
                const int jr = (bb << 11) + (w << 6) + bit;
                float e0 = sd0 + s1s[(size_t)jr * 4 + h0];
                e0 = e0 > 0.f ? e0 : 0.2f * e0;
                float e1 = sd1 + s1s[(size_t)jr * 4 + h1];
                e1 = e1 > 0.f ? e1 : 0.2f * e1;
                const float v0 = hh1[(size_t)jr * HID + lane];
                const float v1 = hh1[(size_t)jr * HID + 64 + lane];
                float nm = fmaxf(m0, e0);
                float sc = __expf(m0 - nm);
                float p  = __expf(e0 - nm);
                l0 = l0 * sc + p; a0 = a0 * sc + p * v0; m0 = nm;
                nm = fmaxf(m1, e1);
                sc = __expf(m1 - nm);
                p  = __expf(e1 - nm);
                l1 = l1 * sc + p; a1 = a1 * sc + p * v1; m1 = nm;
            }
        }
        float o0 = (l0 > 0.f ? a0 / l0 : 0.f) + b1v[lane];
        float o1 = (l1 > 0.f ? a1 / l1 : 0.f) + b1v[64 + lane];
        o0 = 0.5f * o0 * (1.f + erff(o0 * 0.70710678118654752f));
        o1 = 0.5f * o1 * (1.f + erff(o1 * 0.70710678118654752f));
        gl[r][lane]      = o0;
        gl[r][64 + lane] = o1;
    }
    __syncthreads();

    // GEMV: hh2 = g@W2 ; per-head s2 reductions. c = t (128 channels).
    const int c = t;
    float acc[8];
    #pragma unroll
    for (int r = 0; r < 8; ++r) acc[r] = 0.f;
    #pragma unroll 4
    for (int k = 0; k < HID; ++k) {
        const float w = W2[k * HID + c];
        #pragma unroll
        for (int r = 0; r < 8; ++r)
            acc[r] += gl[r][k] * w;                           // LDS broadcast
    }
    const float as = a2s[c], ad = a2d[c];
    #pragma unroll
    for (int r = 0; r < 8; ++r) {
        hh2[(size_t)(r0 + r) * HID + c] = acc[r];
        float vs = acc[r] * as;
        float vd = acc[r] * ad;
        #pragma unroll
        for (int m = 1; m < 32; m <<= 1) {
            vs += __shfl_xor(vs, m, 32);
            vd += __shfl_xor(vd, m, 32);
        }
        if ((c & 31) == 0) {
            s2s[(size_t)(r0 + r) * 4 + (c >> 5)] = vs;
            s2d[(size_t)(r0 + r) * 4 + (c >> 5)] = vd;
        }
    }
}

// ------------- final masked aggregation: 4 rows/block, one wave per row
__global__ __launch_bounds__(256) void k_gat(const float* __restrict__ hh,
                                             const float* __restrict__ ssrc,
                                             const float* __restrict__ sdst,
                                             const u64* __restrict__ maskw,
                                             const float* __restrict__ bias,
                                             float* __restrict__ out) {
    const int row  = blockIdx.x * 4 + (threadIdx.x >> 6);   // b*N + i
    const int i    = row & (Nn - 1);
    const int b    = row >> 11;
    const int lane = threadIdx.x & 63;  // channels: lane (heads 0/1), lane+64 (heads 2/3)
    const int h0   = lane >> 5;
    const int h1   = 2 + h0;
    const float sd0 = sdst[(size_t)row * 4 + h0];
    const float sd1 = sdst[(size_t)row * 4 + h1];
    const u64* mrow = maskw + (size_t)i * NW;

    const u64 myw = (lane < NW) ? mrow[lane] : 0ULL;      // one coalesced round
    u64 nz = __ballot(myw != 0ULL);

    float m0 = -INFINITY, l0 = 0.f, a0 = 0.f;
    float m1 = -INFINITY, l1 = 0.f, a1 = 0.f;

    while (nz) {
        const int w = __builtin_ctzll(nz); nz &= nz - 1;
        u64 word = __shfl(myw, w, 64);
        while (word) {
            const int bit = __builtin_ctzll(word); word &= word - 1;
            const int jr = (b << 11) + (w << 6) + bit;
            float e0 = sd0 + ssrc[(size_t)jr * 4 + h0];
            e0 = e0 > 0.f ? e0 : 0.2f * e0;
            float e1 = sd1 + ssrc[(size_t)jr * 4 + h1];
            e1 = e1 > 0.f ? e1 : 0.2f * e1;
            const float v0 = hh[(size_t)jr * HID + lane];
            const float v1 = hh[(size_t)jr * HID + 64 + lane];
            float nm = fmaxf(m0, e0);
            float sc = __expf(m0 - nm);
            float p  = __expf(e0 - nm);
            l0 = l0 * sc + p; a0 = a0 * sc + p * v0; m0 = nm;
            nm = fmaxf(m1, e1);
            sc = __expf(m1 - nm);
            p  = __expf(e1 - nm);
            l1 = l1 * sc + p; a1 = a1 * sc + p * v1; m1 = nm;
        }
    }

    out[(size_t)row * HID + lane]      = (l0 > 0.f ? a0 / l0 : 0.f) + bias[lane];
    out[(size_t)row * HID + 64 + lane] = (l1 > 0.f ? a1 / l1 : 0.f) + bias[64 + lane];
}

// ---------------------------------------------------------------- launcher
extern "C" void kernel_launch(void* const* d_in, const int* in_sizes, int n_in,
                              void* d_out, int out_size, void* d_ws, size_t ws_size,
                              hipStream_t stream) {
    // dict order: x, embedding, Wp, bp, W1, a1_src, a1_dst, b1, W2, a2_src, a2_dst, b2
    const float* x   = (const float*)d_in[0];
    const float* emb = (const float*)d_in[1];
    const float* Wp  = (const float*)d_in[2];
    const float* bp  = (const float*)d_in[3];
    const float* W1  = (const float*)d_in[4];
    const float* a1s = (const float*)d_in[5];
    const float* a1d = (const float*)d_in[6];
    const float* b1  = (const float*)d_in[7];
    const float* W2  = (const float*)d_in[8];
    const float* a2s = (const float*)d_in[9];
    const float* a2d = (const float*)d_in[10];
    const float* b2  = (const float*)d_in[11];

    // Workspace: ~9 MB
    char* ws = (char*)d_ws;
    u64*  maskw = (u64*)ws;   ws += (size_t)Nn * NW * 8;           // 512 KB
    float* hh1  = (float*)ws; ws += (size_t)Bb * Nn * HID * 4;     // 4 MB
    float* hh2  = (float*)ws; ws += (size_t)Bb * Nn * HID * 4;     // 4 MB
    float* s1s  = (float*)ws; ws += (size_t)Bb * Nn * 4 * 4;       // 128 KB
    float* s1d  = (float*)ws; ws += (size_t)Bb * Nn * 4 * 4;       // 128 KB
    float* s2s  = (float*)ws; ws += (size_t)Bb * Nn * 4 * 4;       // 128 KB
    float* s2d  = (float*)ws; ws += (size_t)Bb * Nn * 4 * 4;       // 128 KB

    k_adjproj<<<NTRI + 512, 256, 0, stream>>>(emb, maskw, x, Wp, bp, W1, a1s, a1d,
                                              hh1, s1s, s1d);
    k_gathid2<<<Bb * Nn / 8, 128, 0, stream>>>(hh1, s1s, s1d, maskw, b1,
                                               W2, a2s, a2d, hh2, s2s, s2d);
    k_gat<<<Bb * Nn / 4, 256, 0, stream>>>(hh2, s2s, s2d, maskw, b2, (float*)d_out);
}

// Round 23
// 47.539 us; speedup vs baseline: 1.0588x; 1.0588x over previous
//
#include <hip/hip_runtime.h>
#include <hip/hip_bf16.h>

using u64 = unsigned long long;

constexpr int Bb    = 4;
constexpr int Nn    = 2048;
constexpr int INDIM = 64;
constexpr int HID   = 128;      // HIDDEN == OUT_DIM == 128
constexpr int NW    = Nn / 64;  // mask words per row = 32
constexpr int NT    = 16;       // 128-wide tile count per dim
constexpr int NTRI  = NT * (NT + 1) / 2;   // 136 upper-triangle tiles

// ---------------- fused: [adj 128x128 upper-triangle tiles + transpose write]
//                      || [projhid]   (r21 exact — best measured)
struct AdjS {
    float As[32][132];          // k-major A tile (128 i-rows)
    float Bs[32][132];          // k-major B tile (128 j-rows)
    float nA[128];              // rsqrt norms, i-rows
    float nB[128];              // rsqrt norms, j-rows
    unsigned char mb [128][16]; // direct bytes: mb[row][colgroup]  (8 cols/byte)
    unsigned char mbT[128][16]; // transposed bytes: mbT[col][rowgroup]
};

__global__ __launch_bounds__(256) void k_adjproj(
        const float* __restrict__ emb, u64* __restrict__ maskw,
        const float* __restrict__ x,   const float* __restrict__ Wp,
        const float* __restrict__ bp,  const float* __restrict__ W1,
        const float* __restrict__ a1s, const float* __restrict__ a1d,
        float* __restrict__ hh1, float* __restrict__ s1s, float* __restrict__ s1d) {
    __shared__ __align__(16) unsigned char smem[sizeof(AdjS)];
    const int t = threadIdx.x;

    if (blockIdx.x < NTRI) {
        // -------- adj: upper-triangle 128x128 tile, 8x8 acc/thread, BK=32
        AdjS& S = *reinterpret_cast<AdjS*>(smem);
        int b = blockIdx.x, ti = 0, cum = 0;
        while (cum + (NT - ti) <= b) { cum += NT - ti; ++ti; }
        const int tj = ti + (b - cum);
        const bool diag = (ti == tj);
        const int i0 = ti * 128, j0 = tj * 128;

        const int tx = t & 15, ty = t >> 4;         // 16x16 thread grid
        const int sr = t >> 1, sh = (t & 1) * 16;   // staging: 2 threads/row, 16 floats

        float acc[8][8];
        #pragma unroll
        for (int a = 0; a < 8; ++a)
            #pragma unroll
            for (int c = 0; c < 8; ++c) acc[a][c] = 0.f;

        float sqa = 0.f, sqb = 0.f;

        for (int kc = 0; kc < HID; kc += 32) {
            const float* gA = emb + (size_t)(i0 + sr) * HID + kc + sh;
            const float* gB = emb + (size_t)(j0 + sr) * HID + kc + sh;
            #pragma unroll
            for (int e = 0; e < 16; e += 4) {
                const float4 va = *reinterpret_cast<const float4*>(gA + e);
                const float4 vb = *reinterpret_cast<const float4*>(gB + e);
                S.As[sh + e + 0][sr] = va.x; S.As[sh + e + 1][sr] = va.y;
                S.As[sh + e + 2][sr] = va.z; S.As[sh + e + 3][sr] = va.w;
                sqa += va.x * va.x + va.y * va.y + va.z * va.z + va.w * va.w;
                S.Bs[sh + e + 0][sr] = vb.x; S.Bs[sh + e + 1][sr] = vb.y;
                S.Bs[sh + e + 2][sr] = vb.z; S.Bs[sh + e + 3][sr] = vb.w;
                sqb += vb.x * vb.x + vb.y * vb.y + vb.z * vb.z + vb.w * vb.w;
            }
            __syncthreads();
            #pragma unroll 4
            for (int k = 0; k < 32; ++k) {
                float a[8], c[8];
                *reinterpret_cast<float4*>(&a[0]) = *reinterpret_cast<const float4*>(&S.As[k][ty * 8]);
                *reinterpret_cast<float4*>(&a[4]) = *reinterpret_cast<const float4*>(&S.As[k][ty * 8 + 4]);
                *reinterpret_cast<float4*>(&c[0]) = *reinterpret_cast<const float4*>(&S.Bs[k][tx * 8]);
                *reinterpret_cast<float4*>(&c[4]) = *reinterpret_cast<const float4*>(&S.Bs[k][tx * 8 + 4]);
                #pragma unroll
                for (int ii = 0; ii < 8; ++ii)
                    #pragma unroll
                    for (int jj = 0; jj < 8; ++jj)
                        acc[ii][jj] += a[ii] * c[jj];
            }
            __syncthreads();
        }

        {
            const float ta = sqa + __shfl_xor(sqa, 1, 64);
            if ((t & 1) == 0) S.nA[sr] = rsqrtf(ta + 1e-12f);
            const float tb = sqb + __shfl_xor(sqb, 1, 64);
            if ((t & 1) == 0) S.nB[sr] = rsqrtf(tb + 1e-12f);
        }
        __syncthreads();

        float rsi[8], rsj[8];
        #pragma unroll
        for (int e = 0; e < 8; ++e) { rsi[e] = S.nA[ty * 8 + e]; rsj[e] = S.nB[tx * 8 + e]; }

        bool bit[8][8];
        #pragma unroll
        for (int e = 0; e < 8; ++e)
            #pragma unroll
            for (int jj = 0; jj < 8; ++jj)
                bit[e][jj] = (acc[e][jj] * rsi[e] * rsj[jj] > 0.5f);

        #pragma unroll
        for (int e = 0; e < 8; ++e) {
            unsigned byte = 0;
            #pragma unroll
            for (int jj = 0; jj < 8; ++jj) if (bit[e][jj]) byte |= (1u << jj);
            S.mb[ty * 8 + e][tx] = (unsigned char)byte;
        }
        #pragma unroll
        for (int jj = 0; jj < 8; ++jj) {
            unsigned byte = 0;
            #pragma unroll
            for (int e = 0; e < 8; ++e) if (bit[e][jj]) byte |= (1u << e);
            S.mbT[tx * 8 + jj][ty] = (unsigned char)byte;
        }
        __syncthreads();

        if (t < 128) {                      // direct: row i0+t, words 2tj, 2tj+1
            const u64* p = reinterpret_cast<const u64*>(S.mb[t]);
            maskw[(size_t)(i0 + t) * NW + 2 * tj]     = p[0];
            maskw[(size_t)(i0 + t) * NW + 2 * tj + 1] = p[1];
        } else if (!diag) {                 // transpose: row j0+(t-128), words 2ti, 2ti+1
            const int c = t - 128;
            const u64* p = reinterpret_cast<const u64*>(S.mbT[c]);
            maskw[(size_t)(j0 + c) * NW + 2 * ti]     = p[0];
            maskw[(size_t)(j0 + c) * NW + 2 * ti + 1] = p[1];
        }
    } else {
        // ---------------- projhid: 16 rows/block (two 128-thread halves x 8)
        float (*hl)[128] = reinterpret_cast<float(*)[128]>(smem);
        const int h  = t >> 7;          // half 0/1
        const int c  = t & 127;         // channel
        const int r0 = (blockIdx.x - NTRI) * 16 + h * 8;

        float acc[8];
        const float bias = bp[c];
        #pragma unroll
        for (int r = 0; r < 8; ++r) acc[r] = bias;
        #pragma unroll 4
        for (int k = 0; k < INDIM; ++k) {
            const float wp = Wp[k * HID + c];
            #pragma unroll
            for (int r = 0; r < 8; ++r)
                acc[r] += x[(size_t)(r0 + r) * INDIM + k] * wp;  // block-uniform -> s_load
        }
        #pragma unroll
        for (int r = 0; r < 8; ++r) hl[h * 8 + r][c] = acc[r];
        __syncthreads();

        float a2[8];
        #pragma unroll
        for (int r = 0; r < 8; ++r) a2[r] = 0.f;
        #pragma unroll 4
        for (int k = 0; k < HID; ++k) {
            const float w = W1[k * HID + c];
            #pragma unroll
            for (int r = 0; r < 8; ++r)
                a2[r] += hl[h * 8 + r][k] * w;                   // LDS broadcast
        }
        const float as = a1s[c], ad = a1d[c];
        #pragma unroll
        for (int r = 0; r < 8; ++r) {
            hh1[(size_t)(r0 + r) * HID + c] = a2[r];
            float vs = a2[r] * as;
            float vd = a2[r] * ad;
            #pragma unroll
            for (int m = 1; m < 32; m <<= 1) {
                vs += __shfl_xor(vs, m, 32);
                vd += __shfl_xor(vd, m, 32);
            }
            if ((c & 31) == 0) {
                s1s[(size_t)(r0 + r) * 4 + (c >> 5)] = vs;
                s1d[(size_t)(r0 + r) * 4 + (c >> 5)] = vd;
            }
        }
    }
}

// ------- merged layer 2: stage-2 (gat1+GELU, hh2, s2 in LDS) + stage-3 (final
// gat -> out). 8 rows/block, 128 threads (2 waves). Neighbor hh2/s2 served
// from LDS when the neighbor is one of the block's 8 rows (always true for the
// diag edge); rare out-of-block edges are recomputed wave-collectively
// (correct for any mask; ~never taken on this data).
__global__ __launch_bounds__(128) void k_layer2(
        const float* __restrict__ hh1,
        const float* __restrict__ s1s, const float* __restrict__ s1d,
        const u64* __restrict__ maskw, const float* __restrict__ b1v,
        const float* __restrict__ W2,
        const float* __restrict__ a2s, const float* __restrict__ a2d,
        const float* __restrict__ b2v, float* __restrict__ out) {
    const int r0    = blockIdx.x * 8;
    const int bb    = r0 >> 11;            // batch (blocks never straddle batches)
    const int iBase = r0 & (Nn - 1);       // local node base
    const int t     = threadIdx.x;
    const int wv    = t >> 6;              // wave 0/1
    const int lane  = t & 63;
    const int h0    = lane >> 5, h1 = 2 + h0;
    __shared__ float gl[8][128];
    __shared__ float h2l[8][128];
    __shared__ float s2sl[8][4];
    __shared__ float s2dl[8][4];

    // ---- Phase A: stage-2 scans (gat1 + GELU) for own 8 rows ----
    for (int rr = 0; rr < 4; ++rr) {
        const int r   = wv * 4 + rr;
        const int row = r0 + r, i = row & (Nn - 1);
        const u64* mrow = maskw + (size_t)i * NW;
        const u64 myw = (lane < NW) ? mrow[lane] : 0ULL;
        u64 nz = __ballot(myw != 0ULL);
        const float sd0 = s1d[(size_t)row * 4 + h0];
        const float sd1 = s1d[(size_t)row * 4 + h1];
        float m0 = -INFINITY, l0 = 0.f, a0 = 0.f;
        float m1 = -INFINITY, l1 = 0.f, a1 = 0.f;
        while (nz) {
            const int w = __builtin_ctzll(nz); nz &= nz - 1;
            u64 word = __shfl(myw, w, 64);
            while (word) {
                const int bit = __builtin_ctzll(word); word &= word - 1;
                const int jr = (bb << 11) + (w << 6) + bit;
                float e0 = sd0 + s1s[(size_t)jr * 4 + h0];
                e0 = e0 > 0.f ? e0 : 0.2f * e0;
                float e1 = sd1 + s1s[(size_t)jr * 4 + h1];
                e1 = e1 > 0.f ? e1 : 0.2f * e1;
                const float v0 = hh1[(size_t)jr * HID + lane];
                const float v1 = hh1[(size_t)jr * HID + 64 + lane];
                float nm = fmaxf(m0, e0);
                float sc = __expf(m0 - nm);
                float p  = __expf(e0 - nm);
                l0 = l0 * sc + p; a0 = a0 * sc + p * v0; m0 = nm;
                nm = fmaxf(m1, e1);
                sc = __expf(m1 - nm);
                p  = __expf(e1 - nm);
                l1 = l1 * sc + p; a1 = a1 * sc + p * v1; m1 = nm;
            }
        }
        float o0 = (l0 > 0.f ? a0 / l0 : 0.f) + b1v[lane];
        float o1 = (l1 > 0.f ? a1 / l1 : 0.f) + b1v[64 + lane];
        o0 = 0.5f * o0 * (1.f + erff(o0 * 0.70710678118654752f));
        o1 = 0.5f * o1 * (1.f + erff(o1 * 0.70710678118654752f));
        gl[r][lane]      = o0;
        gl[r][64 + lane] = o1;
    }
    __syncthreads();

    // ---- Phase B: hh2 = g@W2 ; s2 reductions (into LDS only) ----
    {
        const int c = t;
        float acc[8];
        #pragma unroll
        for (int r = 0; r < 8; ++r) acc[r] = 0.f;
        #pragma unroll 4
        for (int k = 0; k < HID; ++k) {
            const float w = W2[k * HID + c];
            #pragma unroll
            for (int r = 0; r < 8; ++r)
                acc[r] += gl[r][k] * w;                       // LDS broadcast
        }
        const float as = a2s[c], ad = a2d[c];
        #pragma unroll
        for (int r = 0; r < 8; ++r) {
            h2l[r][c] = acc[r];
            float vs = acc[r] * as;
            float vd = acc[r] * ad;
            #pragma unroll
            for (int m = 1; m < 32; m <<= 1) {
                vs += __shfl_xor(vs, m, 32);
                vd += __shfl_xor(vd, m, 32);
            }
            if ((c & 31) == 0) {
                s2sl[r][c >> 5] = vs;
                s2dl[r][c >> 5] = vd;
            }
        }
    }
    __syncthreads();

    // ---- Phase C: stage-3 for own rows -> out ----
    for (int rr = 0; rr < 4; ++rr) {
        const int r   = wv * 4 + rr;
        const int row = r0 + r, i = row & (Nn - 1);
        const u64* mrow = maskw + (size_t)i * NW;
        const u64 myw = (lane < NW) ? mrow[lane] : 0ULL;
        u64 nz = __ballot(myw != 0ULL);
        const float sd0 = s2dl[r][h0];
        const float sd1 = s2dl[r][h1];
        float m0 = -INFINITY, l0 = 0.f, a0 = 0.f;
        float m1 = -INFINITY, l1 = 0.f, a1 = 0.f;
        while (nz) {
            const int w = __builtin_ctzll(nz); nz &= nz - 1;
            u64 word = __shfl(myw, w, 64);
            while (word) {
                const int bit = __builtin_ctzll(word); word &= word - 1;
                const int j = (w << 6) + bit;               // local node index
                float vs0, vs1, v0, v1;
                const unsigned lj = (unsigned)(j - iBase);
                if (lj < 8u) {
                    vs0 = s2sl[lj][h0]; vs1 = s2sl[lj][h1];
                    v0  = h2l[lj][lane]; v1 = h2l[lj][64 + lane];
                } else {
                    // foreign edge: wave-collective stage-2 recompute for j
                    const int jr = (bb << 11) + j;
                    const u64* mrj = maskw + (size_t)j * NW;
                    const u64 myj = (lane < NW) ? mrj[lane] : 0ULL;
                    u64 nzj = __ballot(myj != 0ULL);
                    const float sdj0 = s1d[(size_t)jr * 4 + h0];
                    const float sdj1 = s1d[(size_t)jr * 4 + h1];
                    float fm0 = -INFINITY, fl0 = 0.f, fa0 = 0.f;
                    float fm1 = -INFINITY, fl1 = 0.f, fa1 = 0.f;
                    while (nzj) {
                        const int w2 = __builtin_ctzll(nzj); nzj &= nzj - 1;
                        u64 wd = __shfl(myj, w2, 64);
                        while (wd) {
                            const int b2i = __builtin_ctzll(wd); wd &= wd - 1;
                            const int k2 = (bb << 11) + (w2 << 6) + b2i;
                            float e0 = sdj0 + s1s[(size_t)k2 * 4 + h0];
                            e0 = e0 > 0.f ? e0 : 0.2f * e0;
                            float e1 = sdj1 + s1s[(size_t)k2 * 4 + h1];
                            e1 = e1 > 0.f ? e1 : 0.2f * e1;
                            const float fv0 = hh1[(size_t)k2 * HID + lane];
                            const float fv1 = hh1[(size_t)k2 * HID + 64 + lane];
                            float nm = fmaxf(fm0, e0);
                            float sc = __expf(fm0 - nm);
                            float p  = __expf(e0 - nm);
                            fl0 = fl0 * sc + p; fa0 = fa0 * sc + p * fv0; fm0 = nm;
                            nm = fmaxf(fm1, e1);
                            sc = __expf(fm1 - nm);
                            p  = __expf(e1 - nm);
                            fl1 = fl1 * sc + p; fa1 = fa1 * sc + p * fv1; fm1 = nm;
                        }
                    }
                    float g0 = (fl0 > 0.f ? fa0 / fl0 : 0.f) + b1v[lane];
                    float g1 = (fl1 > 0.f ? fa1 / fl1 : 0.f) + b1v[64 + lane];
                    g0 = 0.5f * g0 * (1.f + erff(g0 * 0.70710678118654752f));
                    g1 = 0.5f * g1 * (1.f + erff(g1 * 0.70710678118654752f));
                    float val0 = 0.f, val1 = 0.f;
                    for (int k = 0; k < 64; ++k) {
                        const float gk = __shfl(g0, k, 64);
                        val0 += gk * W2[k * HID + lane];
                        val1 += gk * W2[k * HID + 64 + lane];
                    }
                    for (int k = 0; k < 64; ++k) {
                        const float gk = __shfl(g1, k, 64);
                        val0 += gk * W2[(64 + k) * HID + lane];
                        val1 += gk * W2[(64 + k) * HID + 64 + lane];
                    }
                    float t0 = val0 * a2s[lane];
                    float t1 = val1 * a2s[64 + lane];
                    #pragma unroll
                    for (int m = 1; m < 32; m <<= 1) {
                        t0 += __shfl_xor(t0, m, 32);
                        t1 += __shfl_xor(t1, m, 32);
                    }
                    vs0 = t0; vs1 = t1; v0 = val0; v1 = val1;
                }
                float e0 = sd0 + vs0;
                e0 = e0 > 0.f ? e0 : 0.2f * e0;
                float e1 = sd1 + vs1;
                e1 = e1 > 0.f ? e1 : 0.2f * e1;
                float nm = fmaxf(m0, e0);
                float sc = __expf(m0 - nm);
                float p  = __expf(e0 - nm);
                l0 = l0 * sc + p; a0 = a0 * sc + p * v0; m0 = nm;
                nm = fmaxf(m1, e1);
                sc = __expf(m1 - nm);
                p  = __expf(e1 - nm);
                l1 = l1 * sc + p; a1 = a1 * sc + p * v1; m1 = nm;
            }
        }
        out[(size_t)row * HID + lane]      = (l0 > 0.f ? a0 / l0 : 0.f) + b2v[lane];
        out[(size_t)row * HID + 64 + lane] = (l1 > 0.f ? a1 / l1 : 0.f) + b2v[64 + lane];
    }
}

// ---------------------------------------------------------------- launcher
extern "C" void kernel_launch(void* const* d_in, const int* in_sizes, int n_in,
                              void* d_out, int out_size, void* d_ws, size_t ws_size,
                              hipStream_t stream) {
    // dict order: x, embedding, Wp, bp, W1, a1_src, a1_dst, b1, W2, a2_src, a2_dst, b2
    const float* x   = (const float*)d_in[0];
    const float* emb = (const float*)d_in[1];
    const float* Wp  = (const float*)d_in[2];
    const float* bp  = (const float*)d_in[3];
    const float* W1  = (const float*)d_in[4];
    const float* a1s = (const float*)d_in[5];
    const float* a1d = (const float*)d_in[6];
    const float* b1  = (const float*)d_in[7];
    const float* W2  = (const float*)d_in[8];
    const float* a2s = (const float*)d_in[9];
    const float* a2d = (const float*)d_in[10];
    const float* b2  = (const float*)d_in[11];

    // Workspace: ~4.8 MB
    char* ws = (char*)d_ws;
    u64*  maskw = (u64*)ws;   ws += (size_t)Nn * NW * 8;           // 512 KB
    float* hh1  = (float*)ws; ws += (size_t)Bb * Nn * HID * 4;     // 4 MB
    float* s1s  = (float*)ws; ws += (size_t)Bb * Nn * 4 * 4;       // 128 KB
    float* s1d  = (float*)ws; ws += (size_t)Bb * Nn * 4 * 4;       // 128 KB

    k_adjproj<<<NTRI + 512, 256, 0, stream>>>(emb, maskw, x, Wp, bp, W1, a1s, a1d,
                                              hh1, s1s, s1d);
    k_layer2<<<Bb * Nn / 8, 128, 0, stream>>>(hh1, s1s, s1d, maskw, b1,
                                              W2, a2s, a2d, b2, (float*)d_out);
}

// Round 24
// 45.881 us; speedup vs baseline: 1.0971x; 1.0361x over previous
//
#include <hip/hip_runtime.h>
#include <hip/hip_bf16.h>

using u64 = unsigned long long;

constexpr int Bb    = 4;
constexpr int Nn    = 2048;
constexpr int INDIM = 64;
constexpr int HID   = 128;      // HIDDEN == OUT_DIM == 128
constexpr int NW    = Nn / 64;  // mask words per row = 32
constexpr int NT    = 16;       // 128-wide tile count per dim
constexpr int NTRI  = NT * (NT + 1) / 2;   // 136 upper-triangle tiles
constexpr int NADJ  = NTRI * 2;            // 272 column-half blocks

// ---------------- fused: [adj 128x64 half-tiles (upper triangle) + transpose]
//                      || [projhid]
// Column-split halves each block's critical path (tail ~halves).
struct AdjS {
    float As[32][132];          // k-major A tile (128 i-rows)
    float Bs[32][68];           // k-major B tile (64 j-cols)
    float nA[128];              // rsqrt norms, i-rows
    float nB[64];               // rsqrt norms, j-cols
    unsigned char mb [128][16]; // direct nibbles: mb[row][tx] (4 cols/nibble)
    unsigned char mbT[64][16];  // transposed bytes: mbT[col][ty] (8 rows/byte)
};

__global__ __launch_bounds__(256) void k_adjproj(
        const float* __restrict__ emb, u64* __restrict__ maskw,
        const float* __restrict__ x,   const float* __restrict__ Wp,
        const float* __restrict__ bp,  const float* __restrict__ W1,
        const float* __restrict__ a1s, const float* __restrict__ a1d,
        float* __restrict__ hh1, float* __restrict__ s1s, float* __restrict__ s1d) {
    __shared__ __align__(16) unsigned char smem[sizeof(AdjS)];
    const int t = threadIdx.x;

    if (blockIdx.x < NADJ) {
        // -------- adj: 128 rows x 64 cols half-tile, 8x4 acc/thread, BK=32
        AdjS& S = *reinterpret_cast<AdjS*>(smem);
        const int colHalf = blockIdx.x & 1;
        int b = blockIdx.x >> 1, ti = 0, cum = 0;
        while (cum + (NT - ti) <= b) { cum += NT - ti; ++ti; }
        const int tj = ti + (b - cum);
        const bool diag = (ti == tj);
        const int i0 = ti * 128, j0 = tj * 128 + colHalf * 64;

        const int tx = t & 15, ty = t >> 4;          // 16x16 thread grid
        const int sra = t >> 1, sha = (t & 1) * 16;  // A staging: 2 thr/row, 16 f
        const int srb = t >> 2, shb = (t & 3) * 8;   // B staging: 4 thr/row, 8 f

        float acc[8][4];
        #pragma unroll
        for (int a = 0; a < 8; ++a)
            #pragma unroll
            for (int c = 0; c < 4; ++c) acc[a][c] = 0.f;

        float sqa = 0.f, sqb = 0.f;

        for (int kc = 0; kc < HID; kc += 32) {
            const float* gA = emb + (size_t)(i0 + sra) * HID + kc + sha;
            const float* gB = emb + (size_t)(j0 + srb) * HID + kc + shb;
            #pragma unroll
            for (int e = 0; e < 16; e += 4) {
                const float4 va = *reinterpret_cast<const float4*>(gA + e);
                S.As[sha + e + 0][sra] = va.x; S.As[sha + e + 1][sra] = va.y;
                S.As[sha + e + 2][sra] = va.z; S.As[sha + e + 3][sra] = va.w;
                sqa += va.x * va.x + va.y * va.y + va.z * va.z + va.w * va.w;
            }
            #pragma unroll
            for (int e = 0; e < 8; e += 4) {
                const float4 vb = *reinterpret_cast<const float4*>(gB + e);
                S.Bs[shb + e + 0][srb] = vb.x; S.Bs[shb + e + 1][srb] = vb.y;
                S.Bs[shb + e + 2][srb] = vb.z; S.Bs[shb + e + 3][srb] = vb.w;
                sqb += vb.x * vb.x + vb.y * vb.y + vb.z * vb.z + vb.w * vb.w;
            }
            __syncthreads();
            #pragma unroll 4
            for (int k = 0; k < 32; ++k) {
                float a[8], c[4];
                *reinterpret_cast<float4*>(&a[0]) = *reinterpret_cast<const float4*>(&S.As[k][ty * 8]);
                *reinterpret_cast<float4*>(&a[4]) = *reinterpret_cast<const float4*>(&S.As[k][ty * 8 + 4]);
                *reinterpret_cast<float4*>(&c[0]) = *reinterpret_cast<const float4*>(&S.Bs[k][tx * 4]);
                #pragma unroll
                for (int ii = 0; ii < 8; ++ii)
                    #pragma unroll
                    for (int jj = 0; jj < 4; ++jj)
                        acc[ii][jj] += a[ii] * c[jj];
            }
            __syncthreads();
        }

        // staging partials -> per-row rsqrt norms
        {
            const float ta = sqa + __shfl_xor(sqa, 1, 64);      // 2 thr/row
            if ((t & 1) == 0) S.nA[sra] = rsqrtf(ta + 1e-12f);
            float tb = sqb + __shfl_xor(sqb, 1, 64);
            tb += __shfl_xor(tb, 2, 64);                         // 4 thr/row
            if ((t & 3) == 0) S.nB[srb] = rsqrtf(tb + 1e-12f);
        }
        __syncthreads();

        float rsi[8], rsj[4];
        #pragma unroll
        for (int e = 0; e < 8; ++e) rsi[e] = S.nA[ty * 8 + e];
        #pragma unroll
        for (int jj = 0; jj < 4; ++jj) rsj[jj] = S.nB[tx * 4 + jj];

        bool bit[8][4];
        #pragma unroll
        for (int e = 0; e < 8; ++e)
            #pragma unroll
            for (int jj = 0; jj < 4; ++jj)
                bit[e][jj] = (acc[e][jj] * rsi[e] * rsj[jj] > 0.5f);

        #pragma unroll
        for (int e = 0; e < 8; ++e) {
            unsigned nib = 0;
            #pragma unroll
            for (int jj = 0; jj < 4; ++jj) if (bit[e][jj]) nib |= (1u << jj);
            S.mb[ty * 8 + e][tx] = (unsigned char)nib;
        }
        #pragma unroll
        for (int jj = 0; jj < 4; ++jj) {
            unsigned byte = 0;
            #pragma unroll
            for (int e = 0; e < 8; ++e) if (bit[e][jj]) byte |= (1u << e);
            S.mbT[tx * 4 + jj][ty] = (unsigned char)byte;
        }
        __syncthreads();

        if (t < 128) {                      // direct: row i0+t, word 2tj+colHalf
            u64 w0 = 0;
            #pragma unroll
            for (int n = 0; n < 16; ++n)
                w0 |= (u64)(S.mb[t][n] & 0xF) << (4 * n);
            maskw[(size_t)(i0 + t) * NW + 2 * tj + colHalf] = w0;
        } else if (t < 192 && !diag) {      // transpose: row j0+(t-128), words 2ti, 2ti+1
            const int c = t - 128;
            const u64* p = reinterpret_cast<const u64*>(S.mbT[c]);
            maskw[(size_t)(j0 + c) * NW + 2 * ti]     = p[0];
            maskw[(size_t)(j0 + c) * NW + 2 * ti + 1] = p[1];
        }
    } else {
        // ---------------- projhid: 16 rows/block (two 128-thread halves x 8)
        float (*hl)[128] = reinterpret_cast<float(*)[128]>(smem);
        const int h  = t >> 7;          // half 0/1
        const int c  = t & 127;         // channel
        const int r0 = (blockIdx.x - NADJ) * 16 + h * 8;

        float acc[8];
        const float bias = bp[c];
        #pragma unroll
        for (int r = 0; r < 8; ++r) acc[r] = bias;
        #pragma unroll 4
        for (int k = 0; k < INDIM; ++k) {
            const float wp = Wp[k * HID + c];
            #pragma unroll
            for (int r = 0; r < 8; ++r)
                acc[r] += x[(size_t)(r0 + r) * INDIM + k] * wp;  // block-uniform -> s_load
        }
        #pragma unroll
        for (int r = 0; r < 8; ++r) hl[h * 8 + r][c] = acc[r];
        __syncthreads();

        float a2[8];
        #pragma unroll
        for (int r = 0; r < 8; ++r) a2[r] = 0.f;
        #pragma unroll 4
        for (int k = 0; k < HID; ++k) {
            const float w = W1[k * HID + c];
            #pragma unroll
            for (int r = 0; r < 8; ++r)
                a2[r] += hl[h * 8 + r][k] * w;                   // LDS broadcast
        }
        const float as = a1s[c], ad = a1d[c];
        #pragma unroll
        for (int r = 0; r < 8; ++r) {
            hh1[(size_t)(r0 + r) * HID + c] = a2[r];
            float vs = a2[r] * as;
            float vd = a2[r] * ad;
            #pragma unroll
            for (int m = 1; m < 32; m <<= 1) {
                vs += __shfl_xor(vs, m, 32);
                vd += __shfl_xor(vd, m, 32);
            }
            if ((c & 31) == 0) {
                s1s[(size_t)(r0 + r) * 4 + (c >> 5)] = vs;
                s1d[(size_t)(r0 + r) * 4 + (c >> 5)] = vd;
            }
        }
    }
}

// ------- merged layer 2: 16 rows/block, 256 threads (4 waves; 4 rows/wave).
__global__ __launch_bounds__(256) void k_layer2(
        const float* __restrict__ hh1,
        const float* __restrict__ s1s, const float* __restrict__ s1d,
        const u64* __restrict__ maskw, const float* __restrict__ b1v,
        const float* __restrict__ W2,
        const float* __restrict__ a2s, const float* __restrict__ a2d,
        const float* __restrict__ b2v, float* __restrict__ out) {
    const int r0    = blockIdx.x * 16;
    const int bb    = r0 >> 11;            // batch (blocks never straddle batches)
    const int iBase = r0 & (Nn - 1);       // local node base
    const int t     = threadIdx.x;
    const int wv    = t >> 6;              // wave 0..3
    const int lane  = t & 63;
    const int h0    = lane >> 5, h1 = 2 + h0;
    __shared__ float gl[16][128];
    __shared__ float h2l[16][128];
    __shared__ float s2sl[16][4];
    __shared__ float s2dl[16][4];

    // ---- Phase A: stage-2 scans (gat1 + GELU) for own 16 rows ----
    for (int rr = 0; rr < 4; ++rr) {
        const int r   = wv * 4 + rr;
        const int row = r0 + r, i = row & (Nn - 1);
        const u64* mrow = maskw + (size_t)i * NW;
        const u64 myw = (lane < NW) ? mrow[lane] : 0ULL;
        u64 nz = __ballot(myw != 0ULL);
        const float sd0 = s1d[(size_t)row * 4 + h0];
        const float sd1 = s1d[(size_t)row * 4 + h1];
        float m0 = -INFINITY, l0 = 0.f, a0 = 0.f;
        float m1 = -INFINITY, l1 = 0.f, a1 = 0.f;
        while (nz) {
            const int w = __builtin_ctzll(nz); nz &= nz - 1;
            u64 word = __shfl(myw, w, 64);
            while (word) {
                const int bit = __builtin_ctzll(word); word &= word - 1;
                const int jr = (bb << 11) + (w << 6) + bit;
                float e0 = sd0 + s1s[(size_t)jr * 4 + h0];
                e0 = e0 > 0.f ? e0 : 0.2f * e0;
                float e1 = sd1 + s1s[(size_t)jr * 4 + h1];
                e1 = e1 > 0.f ? e1 : 0.2f * e1;
                const float v0 = hh1[(size_t)jr * HID + lane];
                const float v1 = hh1[(size_t)jr * HID + 64 + lane];
                float nm = fmaxf(m0, e0);
                float sc = __expf(m0 - nm);
                float p  = __expf(e0 - nm);
                l0 = l0 * sc + p; a0 = a0 * sc + p * v0; m0 = nm;
                nm = fmaxf(m1, e1);
                sc = __expf(m1 - nm);
                p  = __expf(e1 - nm);
                l1 = l1 * sc + p; a1 = a1 * sc + p * v1; m1 = nm;
            }
        }
        float o0 = (l0 > 0.f ? a0 / l0 : 0.f) + b1v[lane];
        float o1 = (l1 > 0.f ? a1 / l1 : 0.f) + b1v[64 + lane];
        o0 = 0.5f * o0 * (1.f + erff(o0 * 0.70710678118654752f));
        o1 = 0.5f * o1 * (1.f + erff(o1 * 0.70710678118654752f));
        gl[r][lane]      = o0;
        gl[r][64 + lane] = o1;
    }
    __syncthreads();

    // ---- Phase B: hh2 = g@W2 ; s2 reductions (into LDS). hf-half owns 8 rows.
    {
        const int c  = t & 127;
        const int hf = t >> 7;
        float acc[8];
        #pragma unroll
        for (int r = 0; r < 8; ++r) acc[r] = 0.f;
        #pragma unroll 4
        for (int k = 0; k < HID; ++k) {
            const float w = W2[k * HID + c];
            #pragma unroll
            for (int r = 0; r < 8; ++r)
                acc[r] += gl[hf * 8 + r][k] * w;              // LDS broadcast
        }
        const float as = a2s[c], ad = a2d[c];
        #pragma unroll
        for (int r = 0; r < 8; ++r) {
            const int rr = hf * 8 + r;
            h2l[rr][c] = acc[r];
            float vs = acc[r] * as;
            float vd = acc[r] * ad;
            #pragma unroll
            for (int m = 1; m < 32; m <<= 1) {
                vs += __shfl_xor(vs, m, 32);
                vd += __shfl_xor(vd, m, 32);
            }
            if ((c & 31) == 0) {
                s2sl[rr][c >> 5] = vs;
                s2dl[rr][c >> 5] = vd;
            }
        }
    }
    __syncthreads();

    // ---- Phase C: stage-3 for own rows -> out ----
    for (int rr = 0; rr < 4; ++rr) {
        const int r   = wv * 4 + rr;
        const int row = r0 + r, i = row & (Nn - 1);
        const u64* mrow = maskw + (size_t)i * NW;
        const u64 myw = (lane < NW) ? mrow[lane] : 0ULL;
        u64 nz = __ballot(myw != 0ULL);
        const float sd0 = s2dl[r][h0];
        const float sd1 = s2dl[r][h1];
        float m0 = -INFINITY, l0 = 0.f, a0 = 0.f;
        float m1 = -INFINITY, l1 = 0.f, a1 = 0.f;
        while (nz) {
            const int w = __builtin_ctzll(nz); nz &= nz - 1;
            u64 word = __shfl(myw, w, 64);
            while (word) {
                const int bit = __builtin_ctzll(word); word &= word - 1;
                const int j = (w << 6) + bit;               // local node index
                float vs0, vs1, v0, v1;
                const unsigned lj = (unsigned)(j - iBase);
                if (lj < 16u) {
                    vs0 = s2sl[lj][h0]; vs1 = s2sl[lj][h1];
                    v0  = h2l[lj][lane]; v1 = h2l[lj][64 + lane];
                } else {
                    // foreign edge: wave-collective stage-2 recompute for j
                    const int jr = (bb << 11) + j;
                    const u64* mrj = maskw + (size_t)j * NW;
                    const u64 myj = (lane < NW) ? mrj[lane] : 0ULL;
                    u64 nzj = __ballot(myj != 0ULL);
                    const float sdj0 = s1d[(size_t)jr * 4 + h0];
                    const float sdj1 = s1d[(size_t)jr * 4 + h1];
                    float fm0 = -INFINITY, fl0 = 0.f, fa0 = 0.f;
                    float fm1 = -INFINITY, fl1 = 0.f, fa1 = 0.f;
                    while (nzj) {
                        const int w2 = __builtin_ctzll(nzj); nzj &= nzj - 1;
                        u64 wd = __shfl(myj, w2, 64);
                        while (wd) {
                            const int b2i = __builtin_ctzll(wd); wd &= wd - 1;
                            const int k2 = (bb << 11) + (w2 << 6) + b2i;
                            float e0 = sdj0 + s1s[(size_t)k2 * 4 + h0];
                            e0 = e0 > 0.f ? e0 : 0.2f * e0;
                            float e1 = sdj1 + s1s[(size_t)k2 * 4 + h1];
                            e1 = e1 > 0.f ? e1 : 0.2f * e1;
                            const float fv0 = hh1[(size_t)k2 * HID + lane];
                            const float fv1 = hh1[(size_t)k2 * HID + 64 + lane];
                            float nm = fmaxf(fm0, e0);
                            float sc = __expf(fm0 - nm);
                            float p  = __expf(e0 - nm);
                            fl0 = fl0 * sc + p; fa0 = fa0 * sc + p * fv0; fm0 = nm;
                            nm = fmaxf(fm1, e1);
                            sc = __expf(fm1 - nm);
                            p  = __expf(e1 - nm);
                            fl1 = fl1 * sc + p; fa1 = fa1 * sc + p * fv1; fm1 = nm;
                        }
                    }
                    float g0 = (fl0 > 0.f ? fa0 / fl0 : 0.f) + b1v[lane];
                    float g1 = (fl1 > 0.f ? fa1 / fl1 : 0.f) + b1v[64 + lane];
                    g0 = 0.5f * g0 * (1.f + erff(g0 * 0.70710678118654752f));
                    g1 = 0.5f * g1 * (1.f + erff(g1 * 0.70710678118654752f));
                    float val0 = 0.f, val1 = 0.f;
                    for (int k = 0; k < 64; ++k) {
                        const float gk = __shfl(g0, k, 64);
                        val0 += gk * W2[k * HID + lane];
                        val1 += gk * W2[k * HID + 64 + lane];
                    }
                    for (int k = 0; k < 64; ++k) {
                        const float gk = __shfl(g1, k, 64);
                        val0 += gk * W2[(64 + k) * HID + lane];
                        val1 += gk * W2[(64 + k) * HID + 64 + lane];
                    }
                    float t0 = val0 * a2s[lane];
                    float t1 = val1 * a2s[64 + lane];
                    #pragma unroll
                    for (int m = 1; m < 32; m <<= 1) {
                        t0 += __shfl_xor(t0, m, 32);
                        t1 += __shfl_xor(t1, m, 32);
                    }
                    vs0 = t0; vs1 = t1; v0 = val0; v1 = val1;
                }
                float e0 = sd0 + vs0;
                e0 = e0 > 0.f ? e0 : 0.2f * e0;
                float e1 = sd1 + vs1;
                e1 = e1 > 0.f ? e1 : 0.2f * e1;
                float nm = fmaxf(m0, e0);
                float sc = __expf(m0 - nm);
                float p  = __expf(e0 - nm);
                l0 = l0 * sc + p; a0 = a0 * sc + p * v0; m0 = nm;
                nm = fmaxf(m1, e1);
                sc = __expf(m1 - nm);
                p  = __expf(e1 - nm);
                l1 = l1 * sc + p; a1 = a1 * sc + p * v1; m1 = nm;
            }
        }
        out[(size_t)row * HID + lane]      = (l0 > 0.f ? a0 / l0 : 0.f) + b2v[lane];
        out[(size_t)row * HID + 64 + lane] = (l1 > 0.f ? a1 / l1 : 0.f) + b2v[64 + lane];
    }
}

// ---------------------------------------------------------------- launcher
extern "C" void kernel_launch(void* const* d_in, const int* in_sizes, int n_in,
                              void* d_out, int out_size, void* d_ws, size_t ws_size,
                              hipStream_t stream) {
    // dict order: x, embedding, Wp, bp, W1, a1_src, a1_dst, b1, W2, a2_src, a2_dst, b2
    const float* x   = (const float*)d_in[0];
    const float* emb = (const float*)d_in[1];
    const float* Wp  = (const float*)d_in[2];
    const float* bp  = (const float*)d_in[3];
    const float* W1  = (const float*)d_in[4];
    const float* a1s = (const float*)d_in[5];
    const float* a1d = (const float*)d_in[6];
    const float* b1  = (const float*)d_in[7];
    const float* W2  = (const float*)d_in[8];
    const float* a2s = (const float*)d_in[9];
    const float* a2d = (const float*)d_in[10];
    const float* b2  = (const float*)d_in[11];

    // Workspace: ~4.8 MB
    char* ws = (char*)d_ws;
    u64*  maskw = (u64*)ws;   ws += (size_t)Nn * NW * 8;           // 512 KB
    float* hh1  = (float*)ws; ws += (size_t)Bb * Nn * HID * 4;     // 4 MB
    float* s1s  = (float*)ws; ws += (size_t)Bb * Nn * 4 * 4;       // 128 KB
    float* s1d  = (float*)ws; ws += (size_t)Bb * Nn * 4 * 4;       // 128 KB

    k_adjproj<<<NADJ + 512, 256, 0, stream>>>(emb, maskw, x, Wp, bp, W1, a1s, a1d,
                                              hh1, s1s, s1d);
    k_layer2<<<Bb * Nn / 16, 256, 0, stream>>>(hh1, s1s, s1d, maskw, b1,
                                               W2, a2s, a2d, b2, (float*)d_out);
}